// Round 1
// baseline (155.125 us; speedup 1.0000x reference)
//
#include <hip/hip_runtime.h>
#include <hip/hip_bf16.h>
#include <stdint.h>

typedef __bf16 bf16x8 __attribute__((ext_vector_type(8)));
typedef float  f32x4  __attribute__((ext_vector_type(4)));

#define NB 32
#define NC 128
#define NH 56
#define NW 56
#define NK 4
#define NCO 128
#define NCR 32
#define NHW 3136
#define TEMPER 30.0f

// ws byte offsets
#define WS_ATTN   0u
#define WS_POOLED 1024u      // 4096 f32
#define WS_BC     20480u     // 4096 f32
#define WS_WC     65536u     // bf16 [32][9][128][128]  = 9,437,184 B
#define WS_XT     10485760u  // bf16 [32][58][58][128]  = 27,557,888 B

__global__ void pool_kernel(const float* __restrict__ x, float* __restrict__ pooled) {
  int bc = blockIdx.x;
  const float* p = x + (size_t)bc * NHW;
  float s = 0.f;
  for (int i = threadIdx.x; i < NHW; i += 256) s += p[i];
  #pragma unroll
  for (int off = 32; off > 0; off >>= 1) s += __shfl_down(s, off);
  __shared__ float red[4];
  if ((threadIdx.x & 63) == 0) red[threadIdx.x >> 6] = s;
  __syncthreads();
  if (threadIdx.x == 0) pooled[bc] = (red[0]+red[1]+red[2]+red[3]) * (1.0f/(float)NHW);
}

__global__ void xt_kernel(const float* __restrict__ x, __hip_bfloat16* __restrict__ xt) {
  int blk = blockIdx.x;            // b*58 + hp
  int b = blk / 58, hp = blk - b*58;
  __hip_bfloat16* orow = xt + (size_t)blk * (58*128);
  int h = hp - 1;
  bool hin = (h >= 0) && (h < NH);
  for (int i = threadIdx.x; i < 58*128; i += 256) {
    int c = i / 58;
    int wp = i - c*58;
    int w = wp - 1;
    float v = 0.f;
    if (hin && w >= 0 && w < NW)
      v = x[(size_t)(b*NC + c)*NHW + h*NW + w];
    orow[wp*128 + c] = __float2bfloat16(v);
  }
}

__global__ void attn_kernel(const float* __restrict__ pooled, const float* __restrict__ aw1,
                            const float* __restrict__ aw2, const float* __restrict__ bias,
                            float* __restrict__ attn, float* __restrict__ bc_out) {
  int b = blockIdx.x;
  __shared__ float sp[NC], h1[NCR], at[NK];
  int t = threadIdx.x;
  if (t < NC) sp[t] = pooled[b*NC + t];
  __syncthreads();
  if (t < NCR) {
    float s = 0.f;
    for (int c = 0; c < NC; ++c) s += aw1[t*NC + c] * sp[c];
    h1[t] = s > 0.f ? s : 0.f;
  }
  __syncthreads();
  if (t == 0) {
    float lg[NK], mx = -1e30f;
    for (int k = 0; k < NK; ++k) {
      float s = 0.f;
      for (int r = 0; r < NCR; ++r) s += aw2[k*NCR + r] * h1[r];
      lg[k] = s * (1.0f/TEMPER);
      mx = fmaxf(mx, lg[k]);
    }
    float den = 0.f, e[NK];
    for (int k = 0; k < NK; ++k) { e[k] = expf(lg[k]-mx); den += e[k]; }
    float inv = 1.0f/den;
    for (int k = 0; k < NK; ++k) { at[k] = e[k]*inv; attn[b*NK+k] = at[k]; }
  }
  __syncthreads();
  if (t < NCO) {
    float s = 0.f;
    for (int k = 0; k < NK; ++k) s += at[k] * bias[k*NCO + t];
    bc_out[b*NCO + t] = s;
  }
}

__global__ void combine_kernel(const float* __restrict__ W, const float* __restrict__ attn,
                               __hip_bfloat16* __restrict__ wc) {
  const int total = NB*9*NCO*NC;   // 4,718,592
  for (int idx = blockIdx.x*256 + threadIdx.x; idx < total; idx += gridDim.x*256) {
    int ci  = idx & 127;
    int co  = (idx >> 7) & 127;
    int rem = idx >> 14;           // b*9 + khw
    int khw = rem % 9;
    int b   = rem / 9;
    const float* a = attn + b*NK;
    size_t wi = (size_t)co*1152 + ci*9 + khw;
    float v = a[0]*W[wi] + a[1]*W[wi+147456] + a[2]*W[wi+2*147456] + a[3]*W[wi+3*147456];
    wc[idx] = __float2bfloat16(v);
  }
}

#define PS 40

#define GLOAD16(src, dst) \
  __builtin_amdgcn_global_load_lds( \
    (const __attribute__((address_space(1))) unsigned int*)(src), \
    (__attribute__((address_space(3))) unsigned int*)(dst), 16, 0, 0)

__global__ __launch_bounds__(256, 2) void conv_kernel(
    const unsigned short* __restrict__ xt,
    const unsigned short* __restrict__ wc,
    const float* __restrict__ bc,
    float* __restrict__ out) {
  __shared__ __align__(16) unsigned short lds_x[6*58*PS];
  __shared__ __align__(16) unsigned short lds_w[128*PS];
  const int tid  = threadIdx.x;
  const int lane = tid & 63;
  const int wv   = tid >> 6;
  const int wave_m = wv & 1;
  const int wave_n = wv >> 1;
  const int bi = blockIdx.x;
  const int b  = bi / 14;
  const int r0 = (bi - b*14) * 4;
  const int li = lane & 15;
  const int kg = lane >> 4;

  int rB[7], cB[7], xoff[7];
  #pragma unroll
  for (int f = 0; f < 7; ++f) {
    int pos = wave_n*112 + f*16 + li;
    rB[f] = pos / 56;
    cB[f] = pos - rB[f]*56;
    xoff[f] = (rB[f]*58 + cB[f])*PS + kg*8;
  }
  const f32x4 vzero = {0.f, 0.f, 0.f, 0.f};
  f32x4 acc[4][7];
  #pragma unroll
  for (int mo = 0; mo < 4; ++mo)
    #pragma unroll
    for (int f = 0; f < 7; ++f) acc[mo][f] = vzero;

  const unsigned short* xtg = xt + (size_t)b*(58*58*128);
  const unsigned short* wcg = wc + (size_t)b*(9*128*128);

  for (int cc = 0; cc < 4; ++cc) {
    __syncthreads();
    #pragma unroll
    for (int i = 0; i < 7; ++i) {
      int q = i*256 + tid;
      int pos = q / 5;
      int part = q - pos*5;
      if (q < 1740 && part < 4) {
        int r = pos / 58;
        int col = pos - r*58;
        const unsigned short* src = xtg + (((r0 + r)*58 + col)*128 + cc*32 + part*8);
        GLOAD16(src, lds_x + (i*2048 + wv*512));
      }
    }
    for (int khw = 0; khw < 9; ++khw) {
      __syncthreads();
      #pragma unroll
      for (int i = 0; i < 3; ++i) {
        int q = i*256 + tid;
        int co = q / 5;
        int part = q - co*5;
        if (q < 640 && part < 4) {
          const unsigned short* src = wcg + ((khw*128 + co)*128 + cc*32 + part*8);
          GLOAD16(src, lds_w + (i*2048 + wv*512));
        }
      }
      __syncthreads();
      const int kh = khw / 3;
      const int kw = khw - kh*3;
      bf16x8 af[4];
      #pragma unroll
      for (int mo = 0; mo < 4; ++mo) {
        int co = wave_m*64 + mo*16 + li;
        af[mo] = *(const bf16x8*)(lds_w + co*PS + kg*8);
      }
      const int koff = (kh*58 + kw)*PS;
      bf16x8 bfr[7];
      #pragma unroll
      for (int f = 0; f < 7; ++f)
        bfr[f] = *(const bf16x8*)(lds_x + xoff[f] + koff);
      #pragma unroll
      for (int mo = 0; mo < 4; ++mo)
        #pragma unroll
        for (int f = 0; f < 7; ++f)
          acc[mo][f] = __builtin_amdgcn_mfma_f32_16x16x32_bf16(af[mo], bfr[f], acc[mo][f], 0, 0, 0);
    }
  }
  float* ob = out + (size_t)b*NCO*NHW;
  #pragma unroll
  for (int mo = 0; mo < 4; ++mo) {
    #pragma unroll
    for (int rg = 0; rg < 4; ++rg) {
      const int co = wave_m*64 + mo*16 + kg*4 + rg;
      const float bv = bc[b*NCO + co];
      float* orow = ob + (size_t)co*NHW;
      #pragma unroll
      for (int f = 0; f < 7; ++f)
        orow[(r0 + rB[f])*56 + cB[f]] = acc[mo][f][rg] + bv;
    }
  }
}

extern "C" void kernel_launch(void* const* d_in, const int* in_sizes, int n_in,
                              void* d_out, int out_size, void* d_ws, size_t ws_size,
                              hipStream_t stream) {
  const float* x   = (const float*)d_in[0];
  const float* W   = (const float*)d_in[1];
  const float* bia = (const float*)d_in[2];
  const float* aw1 = (const float*)d_in[3];
  const float* aw2 = (const float*)d_in[4];
  float* out = (float*)d_out;
  char* ws = (char*)d_ws;
  float* attn   = (float*)(ws + WS_ATTN);
  float* pooled = (float*)(ws + WS_POOLED);
  float* bcm    = (float*)(ws + WS_BC);
  __hip_bfloat16* wc = (__hip_bfloat16*)(ws + WS_WC);
  __hip_bfloat16* xt = (__hip_bfloat16*)(ws + WS_XT);

  pool_kernel<<<NB*NC, 256, 0, stream>>>(x, pooled);
  xt_kernel<<<NB*58, 256, 0, stream>>>(x, xt);
  attn_kernel<<<NB, 128, 0, stream>>>(pooled, aw1, aw2, bia, attn, bcm);
  combine_kernel<<<2048, 256, 0, stream>>>(W, attn, wc);
  conv_kernel<<<NB*14, 256, 0, stream>>>((const unsigned short*)xt,
                                         (const unsigned short*)wc, bcm, out);
}

// Round 2
// 89.379 us; speedup vs baseline: 1.7356x; 1.7356x over previous
//
#include <hip/hip_runtime.h>
#include <hip/hip_bf16.h>
#include <stdint.h>

typedef __bf16 bf16x8 __attribute__((ext_vector_type(8)));
typedef float  f32x4  __attribute__((ext_vector_type(4)));
typedef unsigned short u16x8 __attribute__((ext_vector_type(8)));

#define NB 32
#define NC 128
#define NH 56
#define NW 56
#define NK 4
#define NCO 128
#define NCR 32
#define NHW 3136
#define TEMPER 30.0f

// ws byte offsets
#define WS_ATTN   0u
#define WS_POOLED 1024u      // 4096 f32
#define WS_BC     20480u     // 4096 f32
#define WS_WC     65536u     // bf16 [32][9][128][128]  = 9,437,184 B
#define WS_XT     10485760u  // bf16 [32][58][58][128]  = 27,557,888 B

__global__ void pool_kernel(const float* __restrict__ x, float* __restrict__ pooled) {
  int bc = blockIdx.x;
  const float4* p = (const float4*)(x + (size_t)bc * NHW);  // 784 float4
  float s = 0.f;
  for (int i = threadIdx.x; i < 784; i += 256) {
    float4 v = p[i];
    s += v.x + v.y + v.z + v.w;
  }
  #pragma unroll
  for (int off = 32; off > 0; off >>= 1) s += __shfl_down(s, off);
  __shared__ float red[4];
  if ((threadIdx.x & 63) == 0) red[threadIdx.x >> 6] = s;
  __syncthreads();
  if (threadIdx.x == 0) pooled[bc] = (red[0]+red[1]+red[2]+red[3]) * (1.0f/(float)NHW);
}

// fp32 NCHW -> bf16 [b][hp=58][wp=58][c=128] with zero halo, via LDS transpose.
// Reads coalesced float4 along w; writes coalesced 16B (8 channels) per lane.
__global__ void xt_kernel(const float* __restrict__ x, __hip_bfloat16* __restrict__ xt) {
  __shared__ float lds[58 * 133];          // [wp][c], pad 133 (5-word bank stride)
  int blk = blockIdx.x;                    // b*58 + hp
  int b = blk / 58, hp = blk - b * 58;
  int h = hp - 1;
  bool hin = (h >= 0) && (h < NH);
  int tid = threadIdx.x;
  if (hin) {
    const float* xrow = x + ((size_t)b * NC) * NHW + (size_t)h * NW;  // + c*NHW
    for (int i = tid; i < 128 * 14; i += 256) {   // c x w4
      int c = i / 14;
      int w4 = (i - c * 14) * 4;
      float4 v = *(const float4*)(xrow + (size_t)c * NHW + w4);
      int base = (w4 + 1) * 133 + c;
      lds[base]         = v.x;
      lds[base + 133]   = v.y;
      lds[base + 2*133] = v.z;
      lds[base + 3*133] = v.w;
    }
  }
  __syncthreads();
  __hip_bfloat16* orow = xt + (size_t)blk * (58 * 128);
  for (int i = tid; i < 58 * 16; i += 256) {  // wp x cgroup
    int wp = i >> 4;
    int cg = (i & 15) << 3;
    u16x8 o;
    if (!hin || wp == 0 || wp == 57) {
      o = (u16x8)0;
    } else {
      const float* src = lds + wp * 133 + cg;
      #pragma unroll
      for (int j = 0; j < 8; ++j) {
        union { __hip_bfloat16 b; unsigned short u; } cv;
        cv.b = __float2bfloat16(src[j]);
        o[j] = cv.u;
      }
    }
    *(u16x8*)(orow + wp * 128 + cg) = o;
  }
}

__global__ void attn_kernel(const float* __restrict__ pooled, const float* __restrict__ aw1,
                            const float* __restrict__ aw2, const float* __restrict__ bias,
                            float* __restrict__ attn, float* __restrict__ bc_out) {
  int b = blockIdx.x;
  __shared__ float sp[NC], h1[NCR], at[NK];
  int t = threadIdx.x;
  if (t < NC) sp[t] = pooled[b*NC + t];
  __syncthreads();
  if (t < NCR) {
    float s = 0.f;
    for (int c = 0; c < NC; ++c) s += aw1[t*NC + c] * sp[c];
    h1[t] = s > 0.f ? s : 0.f;
  }
  __syncthreads();
  if (t == 0) {
    float lg[NK], mx = -1e30f;
    for (int k = 0; k < NK; ++k) {
      float s = 0.f;
      for (int r = 0; r < NCR; ++r) s += aw2[k*NCR + r] * h1[r];
      lg[k] = s * (1.0f/TEMPER);
      mx = fmaxf(mx, lg[k]);
    }
    float den = 0.f, e[NK];
    for (int k = 0; k < NK; ++k) { e[k] = expf(lg[k]-mx); den += e[k]; }
    float inv = 1.0f/den;
    for (int k = 0; k < NK; ++k) { at[k] = e[k]*inv; attn[b*NK+k] = at[k]; }
  }
  __syncthreads();
  if (t < NCO) {
    float s = 0.f;
    for (int k = 0; k < NK; ++k) s += at[k] * bias[k*NCO + t];
    bc_out[b*NCO + t] = s;
  }
}

// Wc[b][khw][co][ci] = sum_k attn[b][k] * W[k][co][ci][khw]
// Thread owns (co,ci): reads W[k][co][ci][0..8] contiguously ONCE, loops 8 b's.
__global__ void combine_kernel(const float* __restrict__ W, const float* __restrict__ attn,
                               __hip_bfloat16* __restrict__ wc) {
  int gid = blockIdx.x;                     // 256 blocks
  int bg  = gid >> 6;                       // b-group: 8 b's each
  int tcell = (gid & 63) * 256 + threadIdx.x;  // 0..16383
  int co = tcell >> 7, ci = tcell & 127;
  float w[4][9];
  const float* wp = W + ((size_t)co * 128 + ci) * 9;
  #pragma unroll
  for (int k = 0; k < 4; ++k)
    #pragma unroll
    for (int j = 0; j < 9; ++j)
      w[k][j] = wp[(size_t)k * 147456 + j];
  for (int b = bg * 8; b < bg * 8 + 8; ++b) {
    float a0 = attn[b*4+0], a1 = attn[b*4+1], a2 = attn[b*4+2], a3 = attn[b*4+3];
    #pragma unroll
    for (int j = 0; j < 9; ++j) {
      float v = a0*w[0][j] + a1*w[1][j] + a2*w[2][j] + a3*w[3][j];
      wc[(((size_t)b*9 + j) * 128 + co) * 128 + ci] = __float2bfloat16(v);
    }
  }
}

#define PS 40

#define GLOAD16(src, dst) \
  __builtin_amdgcn_global_load_lds( \
    (const __attribute__((address_space(1))) unsigned int*)(src), \
    (__attribute__((address_space(3))) unsigned int*)(dst), 16, 0, 0)

__global__ __launch_bounds__(256, 2) void conv_kernel(
    const unsigned short* __restrict__ xt,
    const unsigned short* __restrict__ wc,
    const float* __restrict__ bc,
    float* __restrict__ out) {
  __shared__ __align__(16) unsigned short lds_x[6*58*PS];
  __shared__ __align__(16) unsigned short lds_w[128*PS];
  const int tid  = threadIdx.x;
  const int lane = tid & 63;
  const int wv   = tid >> 6;
  const int wave_m = wv & 1;
  const int wave_n = wv >> 1;
  const int bi = blockIdx.x;
  const int b  = bi / 14;
  const int r0 = (bi - b*14) * 4;
  const int li = lane & 15;
  const int kg = lane >> 4;

  int rB[7], cB[7], xoff[7];
  #pragma unroll
  for (int f = 0; f < 7; ++f) {
    int pos = wave_n*112 + f*16 + li;
    rB[f] = pos / 56;
    cB[f] = pos - rB[f]*56;
    xoff[f] = (rB[f]*58 + cB[f])*PS + kg*8;
  }
  const f32x4 vzero = {0.f, 0.f, 0.f, 0.f};
  f32x4 acc[4][7];
  #pragma unroll
  for (int mo = 0; mo < 4; ++mo)
    #pragma unroll
    for (int f = 0; f < 7; ++f) acc[mo][f] = vzero;

  const unsigned short* xtg = xt + (size_t)b*(58*58*128);
  const unsigned short* wcg = wc + (size_t)b*(9*128*128);

  for (int cc = 0; cc < 4; ++cc) {
    __syncthreads();
    #pragma unroll
    for (int i = 0; i < 7; ++i) {
      int q = i*256 + tid;
      int pos = q / 5;
      int part = q - pos*5;
      if (q < 1740 && part < 4) {
        int r = pos / 58;
        int col = pos - r*58;
        const unsigned short* src = xtg + (((r0 + r)*58 + col)*128 + cc*32 + part*8);
        GLOAD16(src, lds_x + (i*2048 + wv*512));
      }
    }
    for (int khw = 0; khw < 9; ++khw) {
      __syncthreads();
      #pragma unroll
      for (int i = 0; i < 3; ++i) {
        int q = i*256 + tid;
        int co = q / 5;
        int part = q - co*5;
        if (q < 640 && part < 4) {
          const unsigned short* src = wcg + ((khw*128 + co)*128 + cc*32 + part*8);
          GLOAD16(src, lds_w + (i*2048 + wv*512));
        }
      }
      __syncthreads();
      const int kh = khw / 3;
      const int kw = khw - kh*3;
      bf16x8 af[4];
      #pragma unroll
      for (int mo = 0; mo < 4; ++mo) {
        int co = wave_m*64 + mo*16 + li;
        af[mo] = *(const bf16x8*)(lds_w + co*PS + kg*8);
      }
      const int koff = (kh*58 + kw)*PS;
      bf16x8 bfr[7];
      #pragma unroll
      for (int f = 0; f < 7; ++f)
        bfr[f] = *(const bf16x8*)(lds_x + xoff[f] + koff);
      #pragma unroll
      for (int mo = 0; mo < 4; ++mo)
        #pragma unroll
        for (int f = 0; f < 7; ++f)
          acc[mo][f] = __builtin_amdgcn_mfma_f32_16x16x32_bf16(af[mo], bfr[f], acc[mo][f], 0, 0, 0);
    }
  }
  float* ob = out + (size_t)b*NCO*NHW;
  #pragma unroll
  for (int mo = 0; mo < 4; ++mo) {
    #pragma unroll
    for (int rg = 0; rg < 4; ++rg) {
      const int co = wave_m*64 + mo*16 + kg*4 + rg;
      const float bv = bc[b*NCO + co];
      float* orow = ob + (size_t)co*NHW;
      #pragma unroll
      for (int f = 0; f < 7; ++f)
        orow[(r0 + rB[f])*56 + cB[f]] = acc[mo][f][rg] + bv;
    }
  }
}

extern "C" void kernel_launch(void* const* d_in, const int* in_sizes, int n_in,
                              void* d_out, int out_size, void* d_ws, size_t ws_size,
                              hipStream_t stream) {
  const float* x   = (const float*)d_in[0];
  const float* W   = (const float*)d_in[1];
  const float* bia = (const float*)d_in[2];
  const float* aw1 = (const float*)d_in[3];
  const float* aw2 = (const float*)d_in[4];
  float* out = (float*)d_out;
  char* ws = (char*)d_ws;
  float* attn   = (float*)(ws + WS_ATTN);
  float* pooled = (float*)(ws + WS_POOLED);
  float* bcm    = (float*)(ws + WS_BC);
  __hip_bfloat16* wc = (__hip_bfloat16*)(ws + WS_WC);
  __hip_bfloat16* xt = (__hip_bfloat16*)(ws + WS_XT);

  pool_kernel<<<NB*NC, 256, 0, stream>>>(x, pooled);
  attn_kernel<<<NB, 128, 0, stream>>>(pooled, aw1, aw2, bia, attn, bcm);
  combine_kernel<<<256, 256, 0, stream>>>(W, attn, wc);
  xt_kernel<<<NB*58, 256, 0, stream>>>(x, xt);
  conv_kernel<<<NB*14, 256, 0, stream>>>((const unsigned short*)xt,
                                         (const unsigned short*)wc, bcm, out);
}

// Round 3
// 79.753 us; speedup vs baseline: 1.9451x; 1.1207x over previous
//
#include <hip/hip_runtime.h>
#include <hip/hip_bf16.h>
#include <stdint.h>

typedef __bf16 bf16x8 __attribute__((ext_vector_type(8)));
typedef float  f32x4  __attribute__((ext_vector_type(4)));
typedef unsigned short u16x8 __attribute__((ext_vector_type(8)));

#define NB 32
#define NC 128
#define NH 56
#define NW 56
#define NK 4
#define NCO 128
#define NCR 32
#define NHW 3136
#define TEMPER 30.0f

// ws byte offsets
#define WS_ATTN   0u         // 512 B
#define WS_BC     4096u      // 16 KB
#define WS_ROWSUM 65536u     // f32 [32][58][128] = 950,272 B
#define WS_WC     1048576u   // bf16 [32][9][128][128] = 9,437,184 B
#define WS_XT     10485760u  // bf16 [32][58][58][128] = 27,557,888 B

// fp32 NCHW -> bf16 [b][hp=58][wp=58][c=128] with zero halo, via LDS transpose.
// Also emits rowsum[b][hp][c] = sum_w x[b,c,h,:] (pool fused in).
__global__ void xt_kernel(const float* __restrict__ x, __hip_bfloat16* __restrict__ xt,
                          float* __restrict__ rowsum) {
  __shared__ float lds[58 * 133];          // [wp][c], pad 133
  int blk = blockIdx.x;                    // b*58 + hp
  int b = blk / 58, hp = blk - b * 58;
  int h = hp - 1;
  bool hin = (h >= 0) && (h < NH);
  int tid = threadIdx.x;
  if (hin) {
    const float* xrow = x + ((size_t)b * NC) * NHW + (size_t)h * NW;
    for (int i = tid; i < 128 * 14; i += 256) {   // c x w4
      int c = i / 14;
      int w4 = (i - c * 14) * 4;
      float4 v = *(const float4*)(xrow + (size_t)c * NHW + w4);
      int base = (w4 + 1) * 133 + c;
      lds[base]         = v.x;
      lds[base + 133]   = v.y;
      lds[base + 2*133] = v.z;
      lds[base + 3*133] = v.w;
    }
  }
  __syncthreads();
  __hip_bfloat16* orow = xt + (size_t)blk * (58 * 128);
  for (int i = tid; i < 58 * 16; i += 256) {  // wp x cgroup
    int wp = i >> 4;
    int cg = (i & 15) << 3;
    u16x8 o;
    if (!hin || wp == 0 || wp == 57) {
      o = (u16x8)0;
    } else {
      const float* src = lds + wp * 133 + cg;
      #pragma unroll
      for (int j = 0; j < 8; ++j) {
        union { __hip_bfloat16 b; unsigned short u; } cv;
        cv.b = __float2bfloat16(src[j]);
        o[j] = cv.u;
      }
    }
    *(u16x8*)(orow + wp * 128 + cg) = o;
  }
  if (hin && tid < 128) {           // fused pool partial: sum over w for channel c
    float s = 0.f;
    #pragma unroll 8
    for (int wp = 1; wp <= 56; ++wp) s += lds[wp * 133 + tid];
    rowsum[(size_t)blk * 128 + tid] = s;
  }
}

__global__ void attn_kernel(const float* __restrict__ rowsum, const float* __restrict__ aw1,
                            const float* __restrict__ aw2, const float* __restrict__ bias,
                            float* __restrict__ attn, float* __restrict__ bc_out) {
  int b = blockIdx.x;
  __shared__ float sp[NC], h1[NCR], at[NK];
  int t = threadIdx.x;
  if (t < NC) {
    float s = 0.f;
    for (int hp = 1; hp <= 56; ++hp) s += rowsum[((size_t)b * 58 + hp) * 128 + t];
    sp[t] = s * (1.0f / (float)NHW);
  }
  __syncthreads();
  if (t < NCR) {
    float s = 0.f;
    for (int c = 0; c < NC; ++c) s += aw1[t*NC + c] * sp[c];
    h1[t] = s > 0.f ? s : 0.f;
  }
  __syncthreads();
  if (t == 0) {
    float lg[NK], mx = -1e30f;
    for (int k = 0; k < NK; ++k) {
      float s = 0.f;
      for (int r = 0; r < NCR; ++r) s += aw2[k*NCR + r] * h1[r];
      lg[k] = s * (1.0f/TEMPER);
      mx = fmaxf(mx, lg[k]);
    }
    float den = 0.f, e[NK];
    for (int k = 0; k < NK; ++k) { e[k] = expf(lg[k]-mx); den += e[k]; }
    float inv = 1.0f/den;
    for (int k = 0; k < NK; ++k) { at[k] = e[k]*inv; attn[b*NK+k] = at[k]; }
  }
  __syncthreads();
  if (t < NCO) {
    float s = 0.f;
    for (int k = 0; k < NK; ++k) s += at[k] * bias[k*NCO + t];
    bc_out[b*NCO + t] = s;
  }
}

// Wc[b][khw][co][ci] = sum_k attn[b][k] * W[k][co][ci][khw]
__global__ void combine_kernel(const float* __restrict__ W, const float* __restrict__ attn,
                               __hip_bfloat16* __restrict__ wc) {
  int gid = blockIdx.x;                     // 256 blocks
  int bg  = gid >> 6;                       // b-group: 8 b's each
  int tcell = (gid & 63) * 256 + threadIdx.x;  // 0..16383
  int co = tcell >> 7, ci = tcell & 127;
  float w[4][9];
  const float* wp = W + ((size_t)co * 128 + ci) * 9;
  #pragma unroll
  for (int k = 0; k < 4; ++k)
    #pragma unroll
    for (int j = 0; j < 9; ++j)
      w[k][j] = wp[(size_t)k * 147456 + j];
  for (int b = bg * 8; b < bg * 8 + 8; ++b) {
    float a0 = attn[b*4+0], a1 = attn[b*4+1], a2 = attn[b*4+2], a3 = attn[b*4+3];
    #pragma unroll
    for (int j = 0; j < 9; ++j) {
      float v = a0*w[0][j] + a1*w[1][j] + a2*w[2][j] + a3*w[3][j];
      wc[(((size_t)b*9 + j) * 128 + co) * 128 + ci] = __float2bfloat16(v);
    }
  }
}

// ------------------------------ conv ------------------------------
// Implicit GEMM, M=128 co, N=224 pos (4 out rows), K=1152 (4 ci-chunks x 9 khw).
// A (weights) read direct from global (L2, XCD-local). B (x) double-buffered in
// LDS with row-padded layout: row stride 2368 shorts (4736 B = 296 slots, %8==0)
// -> ds_read_b128 slot = (5*cB+kg)%8 perfectly distributed, straddle-proof.
#define RS 2368   // shorts per padded LDS row
#define CS 40     // shorts per col cell (4x16B data + 16B pad)
#define BUFSH (6*RS)  // 14208 shorts per buffer

#define GLOAD16(src, dst) \
  __builtin_amdgcn_global_load_lds( \
    (const __attribute__((address_space(1))) unsigned int*)(src), \
    (__attribute__((address_space(3))) unsigned int*)(dst), 16, 0, 0)

__global__ __launch_bounds__(256, 2) void conv_kernel(
    const unsigned short* __restrict__ xt,
    const unsigned short* __restrict__ wc,
    const float* __restrict__ bc,
    float* __restrict__ out) {
  __shared__ __align__(16) unsigned short lds_x[2*BUFSH];  // 56832 B
  const int tid  = threadIdx.x;
  const int lane = tid & 63;
  const int wv   = tid >> 6;
  const int wave_m = wv & 1;
  const int wave_n = wv >> 1;
  // XCD-aware mapping: bid%8 = xcd, 4 b's per XCD, all 14 strips of a b co-XCD.
  const int bid = blockIdx.x;            // 448 = 8*56
  const int xcd = bid & 7;
  const int jj  = bid >> 3;              // 0..55
  const int b   = xcd * 4 + (jj / 14);
  const int r0  = (jj % 14) * 4;
  const int li = lane & 15;
  const int kg = lane >> 4;

  // staging source offsets (fixed per thread across cc): 7 x 256 covers 1776 slots
  int srcoff[7];
  #pragma unroll
  for (int i = 0; i < 7; ++i) {
    int q = i*256 + tid;
    int r = q / 296;
    int sl = q - r*296;
    int col = sl / 5;
    int part = sl - col*5;
    if (q < 1776 && col < 58 && part < 4)
      srcoff[i] = ((r0 + r)*58 + col)*128 + part*8;   // + cc*32 at stage time
    else
      srcoff[i] = -1;
  }

  int rB[7], cB[7], xoff[7];
  #pragma unroll
  for (int f = 0; f < 7; ++f) {
    int pos = wave_n*112 + f*16 + li;
    rB[f] = pos / 56;
    cB[f] = pos - rB[f]*56;
    xoff[f] = rB[f]*RS + cB[f]*CS + kg*8;
  }
  const f32x4 vzero = {0.f, 0.f, 0.f, 0.f};
  f32x4 acc[4][7];
  #pragma unroll
  for (int mo = 0; mo < 4; ++mo)
    #pragma unroll
    for (int f = 0; f < 7; ++f) acc[mo][f] = vzero;

  const unsigned short* xtg = xt + (size_t)b*(58*58*128);
  // per-lane A base: row = wave_m*64 + li (+mo*16), col = kg*8 (+cc*32)
  const unsigned short* wcA = wc + (size_t)b*(9*128*128) + (wave_m*64 + li)*128 + kg*8;

  #define STAGE(bufidx, cc) do { \
    unsigned short* dbase = lds_x + (bufidx)*BUFSH; \
    _Pragma("unroll") \
    for (int i = 0; i < 7; ++i) { \
      if (srcoff[i] >= 0) \
        GLOAD16(xtg + srcoff[i] + (cc)*32, dbase + i*2048 + wv*512); \
    } \
  } while (0)

  STAGE(0, 0);
  __syncthreads();

  for (int cc = 0; cc < 4; ++cc) {
    if (cc < 3) STAGE((cc + 1) & 1, cc + 1);
    const unsigned short* bx = lds_x + (cc & 1)*BUFSH;
    #pragma unroll
    for (int khw = 0; khw < 9; ++khw) {
      const int kh = khw / 3;
      const int kw = khw - kh*3;
      bf16x8 af[4];
      #pragma unroll
      for (int mo = 0; mo < 4; ++mo)
        af[mo] = *(const bf16x8*)(wcA + khw*16384 + mo*2048 + cc*32);
      const int koff = kh*RS + kw*CS;
      bf16x8 bfr[7];
      #pragma unroll
      for (int f = 0; f < 7; ++f)
        bfr[f] = *(const bf16x8*)(bx + xoff[f] + koff);
      #pragma unroll
      for (int mo = 0; mo < 4; ++mo)
        #pragma unroll
        for (int f = 0; f < 7; ++f)
          acc[mo][f] = __builtin_amdgcn_mfma_f32_16x16x32_bf16(af[mo], bfr[f], acc[mo][f], 0, 0, 0);
    }
    __syncthreads();   // drains staged gloads (vmcnt0) + all reads of current buf
  }

  float* ob = out + (size_t)b*NCO*NHW;
  #pragma unroll
  for (int mo = 0; mo < 4; ++mo) {
    #pragma unroll
    for (int rg = 0; rg < 4; ++rg) {
      const int co = wave_m*64 + mo*16 + kg*4 + rg;
      const float bv = bc[b*NCO + co];
      float* orow = ob + (size_t)co*NHW;
      #pragma unroll
      for (int f = 0; f < 7; ++f)
        orow[(r0 + rB[f])*56 + cB[f]] = acc[mo][f][rg] + bv;
    }
  }
}

extern "C" void kernel_launch(void* const* d_in, const int* in_sizes, int n_in,
                              void* d_out, int out_size, void* d_ws, size_t ws_size,
                              hipStream_t stream) {
  const float* x   = (const float*)d_in[0];
  const float* W   = (const float*)d_in[1];
  const float* bia = (const float*)d_in[2];
  const float* aw1 = (const float*)d_in[3];
  const float* aw2 = (const float*)d_in[4];
  float* out = (float*)d_out;
  char* ws = (char*)d_ws;
  float* attn   = (float*)(ws + WS_ATTN);
  float* bcm    = (float*)(ws + WS_BC);
  float* rowsum = (float*)(ws + WS_ROWSUM);
  __hip_bfloat16* wc = (__hip_bfloat16*)(ws + WS_WC);
  __hip_bfloat16* xt = (__hip_bfloat16*)(ws + WS_XT);

  xt_kernel<<<NB*58, 256, 0, stream>>>(x, xt, rowsum);
  attn_kernel<<<NB, 128, 0, stream>>>(rowsum, aw1, aw2, bia, attn, bcm);
  combine_kernel<<<256, 256, 0, stream>>>(W, attn, wc);
  conv_kernel<<<448, 256, 0, stream>>>((const unsigned short*)xt,
                                       (const unsigned short*)wc, bcm, out);
}

// Round 4
// 76.540 us; speedup vs baseline: 2.0267x; 1.0420x over previous
//
#include <hip/hip_runtime.h>
#include <hip/hip_bf16.h>
#include <stdint.h>

typedef __bf16 bf16x8 __attribute__((ext_vector_type(8)));
typedef float  f32x4  __attribute__((ext_vector_type(4)));
typedef unsigned short u16x8 __attribute__((ext_vector_type(8)));

#define NB 32
#define NC 128
#define NH 56
#define NW 56
#define NK 4
#define NCO 128
#define NCR 32
#define NHW 3136
#define TEMPER 30.0f

// ws byte offsets
#define WS_ATTN   0u         // 512 B
#define WS_BC     4096u      // 16 KB
#define WS_ROWSUM 65536u     // f32 [32][58][128] = 950,272 B
#define WS_WC     1048576u   // bf16 [32][9][128][128] = 9,437,184 B
#define WS_XT     10485760u  // bf16 [32][58][58][128] = 27,557,888 B

// fp32 NCHW -> bf16 [b][hp=58][wp=58][c=128] with zero halo, via LDS transpose.
// XCD-aligned: block's b satisfies b/4 == XCD (bid%8), matching conv's map, so
// conv's global_load_lds staging hits local L2. Also emits rowsum (pool fused).
__global__ void xt_kernel(const float* __restrict__ x, __hip_bfloat16* __restrict__ xt,
                          float* __restrict__ rowsum) {
  __shared__ float lds[58 * 133];          // [wp][c], pad 133
  int xcd = blockIdx.x & 7;
  int j   = blockIdx.x >> 3;               // 0..231
  int b   = xcd * 4 + j / 58;
  int hp  = j % 58;
  int blk = b * 58 + hp;
  int h = hp - 1;
  bool hin = (h >= 0) && (h < NH);
  int tid = threadIdx.x;
  if (hin) {
    const float* xrow = x + ((size_t)b * NC) * NHW + (size_t)h * NW;
    for (int i = tid; i < 128 * 14; i += 256) {   // c x w4
      int c = i / 14;
      int w4 = (i - c * 14) * 4;
      float4 v = *(const float4*)(xrow + (size_t)c * NHW + w4);
      int base = (w4 + 1) * 133 + c;
      lds[base]         = v.x;
      lds[base + 133]   = v.y;
      lds[base + 2*133] = v.z;
      lds[base + 3*133] = v.w;
    }
  }
  __syncthreads();
  __hip_bfloat16* orow = xt + (size_t)blk * (58 * 128);
  for (int i = tid; i < 58 * 16; i += 256) {  // wp x cgroup
    int wp = i >> 4;
    int cg = (i & 15) << 3;
    u16x8 o;
    if (!hin || wp == 0 || wp == 57) {
      o = (u16x8)0;
    } else {
      const float* src = lds + wp * 133 + cg;
      #pragma unroll
      for (int jx = 0; jx < 8; ++jx) {
        union { __hip_bfloat16 b; unsigned short u; } cv;
        cv.b = __float2bfloat16(src[jx]);
        o[jx] = cv.u;
      }
    }
    *(u16x8*)(orow + wp * 128 + cg) = o;
  }
  if (hin && tid < 128) {
    float s = 0.f;
    #pragma unroll 8
    for (int wp = 1; wp <= 56; ++wp) s += lds[wp * 133 + tid];
    rowsum[(size_t)blk * 128 + tid] = s;
  }
}

__global__ void attn_kernel(const float* __restrict__ rowsum, const float* __restrict__ aw1,
                            const float* __restrict__ aw2, const float* __restrict__ bias,
                            float* __restrict__ attn, float* __restrict__ bc_out) {
  int b = blockIdx.x;
  __shared__ float sp[NC], h1[NCR], at[NK];
  int t = threadIdx.x;
  if (t < NC) {
    float s = 0.f;
    for (int hp = 1; hp <= 56; ++hp) s += rowsum[((size_t)b * 58 + hp) * 128 + t];
    sp[t] = s * (1.0f / (float)NHW);
  }
  __syncthreads();
  if (t < NCR) {
    float s = 0.f;
    for (int c = 0; c < NC; ++c) s += aw1[t*NC + c] * sp[c];
    h1[t] = s > 0.f ? s : 0.f;
  }
  __syncthreads();
  if (t == 0) {
    float lg[NK], mx = -1e30f;
    for (int k = 0; k < NK; ++k) {
      float s = 0.f;
      for (int r = 0; r < NCR; ++r) s += aw2[k*NCR + r] * h1[r];
      lg[k] = s * (1.0f/TEMPER);
      mx = fmaxf(mx, lg[k]);
    }
    float den = 0.f, e[NK];
    for (int k = 0; k < NK; ++k) { e[k] = expf(lg[k]-mx); den += e[k]; }
    float inv = 1.0f/den;
    for (int k = 0; k < NK; ++k) { at[k] = e[k]*inv; attn[b*NK+k] = at[k]; }
  }
  __syncthreads();
  if (t < NCO) {
    float s = 0.f;
    for (int k = 0; k < NK; ++k) s += at[k] * bias[k*NCO + t];
    bc_out[b*NCO + t] = s;
  }
}

// Wc[b][khw][co][ci] = sum_k attn[b][k] * W[k][co][ci][khw]
__global__ void combine_kernel(const float* __restrict__ W, const float* __restrict__ attn,
                               __hip_bfloat16* __restrict__ wc) {
  int gid = blockIdx.x;                     // 256 blocks
  int bg  = gid >> 6;                       // b-group: 8 b's each
  int tcell = (gid & 63) * 256 + threadIdx.x;  // 0..16383
  int co = tcell >> 7, ci = tcell & 127;
  float w[4][9];
  const float* wp = W + ((size_t)co * 128 + ci) * 9;
  #pragma unroll
  for (int k = 0; k < 4; ++k)
    #pragma unroll
    for (int j = 0; j < 9; ++j)
      w[k][j] = wp[(size_t)k * 147456 + j];
  for (int b = bg * 8; b < bg * 8 + 8; ++b) {
    float a0 = attn[b*4+0], a1 = attn[b*4+1], a2 = attn[b*4+2], a3 = attn[b*4+3];
    #pragma unroll
    for (int j = 0; j < 9; ++j) {
      float v = a0*w[0][j] + a1*w[1][j] + a2*w[2][j] + a3*w[3][j];
      wc[(((size_t)b*9 + j) * 128 + co) * 128 + ci] = __float2bfloat16(v);
    }
  }
}

// ------------------------------ conv ------------------------------
// Implicit GEMM, M=128 co, N=224 pos (4 out rows), K=1152 (4 ci-chunks x 9 khw).
// A (weights) direct from XCD-local L2 with EXPLICIT 1-khw-ahead register
// prefetch (afc/afn ping-pong) so the ~200-900cy load latency hides under the
// previous iteration's MFMAs. B (x) double-buffered LDS, row stride %8==0 slots.
#define RS 2368   // shorts per padded LDS row
#define CS 40     // shorts per col cell (4x16B data + 16B pad)
#define BUFSH (6*RS)

#define GLOAD16(src, dst) \
  __builtin_amdgcn_global_load_lds( \
    (const __attribute__((address_space(1))) unsigned int*)(src), \
    (__attribute__((address_space(3))) unsigned int*)(dst), 16, 0, 0)

__global__ __launch_bounds__(256, 2) void conv_kernel(
    const unsigned short* __restrict__ xt,
    const unsigned short* __restrict__ wc,
    const float* __restrict__ bc,
    float* __restrict__ out) {
  __shared__ __align__(16) unsigned short lds_x[2*BUFSH];
  const int tid  = threadIdx.x;
  const int lane = tid & 63;
  const int wv   = tid >> 6;
  const int wave_m = wv & 1;
  const int wave_n = wv >> 1;
  const int bid = blockIdx.x;            // 448 = 8*56
  const int xcd = bid & 7;
  const int jj  = bid >> 3;              // 0..55
  const int b   = xcd * 4 + (jj / 14);
  const int r0  = (jj % 14) * 4;
  const int li = lane & 15;
  const int kg = lane >> 4;

  int srcoff[7];
  #pragma unroll
  for (int i = 0; i < 7; ++i) {
    int q = i*256 + tid;
    int r = q / 296;
    int sl = q - r*296;
    int col = sl / 5;
    int part = sl - col*5;
    if (q < 1776 && col < 58 && part < 4)
      srcoff[i] = ((r0 + r)*58 + col)*128 + part*8;
    else
      srcoff[i] = -1;
  }

  int rB[7], cB[7], xoff[7];
  #pragma unroll
  for (int f = 0; f < 7; ++f) {
    int pos = wave_n*112 + f*16 + li;
    rB[f] = pos / 56;
    cB[f] = pos - rB[f]*56;
    xoff[f] = rB[f]*RS + cB[f]*CS + kg*8;
  }
  const f32x4 vzero = {0.f, 0.f, 0.f, 0.f};
  f32x4 acc[4][7];
  #pragma unroll
  for (int mo = 0; mo < 4; ++mo)
    #pragma unroll
    for (int f = 0; f < 7; ++f) acc[mo][f] = vzero;

  const unsigned short* xtg = xt + (size_t)b*(58*58*128);
  const unsigned short* wcA = wc + (size_t)b*(9*128*128) + (wave_m*64 + li)*128 + kg*8;

  #define STAGE(bufidx, cc) do { \
    unsigned short* dbase = lds_x + (bufidx)*BUFSH; \
    _Pragma("unroll") \
    for (int i = 0; i < 7; ++i) { \
      if (srcoff[i] >= 0) \
        GLOAD16(xtg + srcoff[i] + (cc)*32, dbase + i*2048 + wv*512); \
    } \
  } while (0)

  #define LOADA(dst, cc, khw) do { \
    _Pragma("unroll") \
    for (int mo = 0; mo < 4; ++mo) \
      dst[mo] = *(const bf16x8*)(wcA + (khw)*16384 + mo*2048 + (cc)*32); \
  } while (0)

  bf16x8 afc[4], afn[4];
  LOADA(afc, 0, 0);        // overlaps initial stage drain
  STAGE(0, 0);
  __syncthreads();

  for (int cc = 0; cc < 4; ++cc) {
    if (cc < 3) STAGE((cc + 1) & 1, cc + 1);
    const unsigned short* bx = lds_x + (cc & 1)*BUFSH;
    #pragma unroll
    for (int khw = 0; khw < 9; ++khw) {
      // prefetch A for the NEXT iteration (crosses cc boundary; global loads
      // are independent of the LDS barrier/buffers)
      if (khw < 8)      LOADA(afn, cc, khw + 1);
      else if (cc < 3)  LOADA(afn, cc + 1, 0);
      const int kh = khw / 3;
      const int kw = khw - kh*3;
      const int koff = kh*RS + kw*CS;
      bf16x8 bfr[7];
      #pragma unroll
      for (int f = 0; f < 7; ++f)
        bfr[f] = *(const bf16x8*)(bx + xoff[f] + koff);
      #pragma unroll
      for (int mo = 0; mo < 4; ++mo)
        #pragma unroll
        for (int f = 0; f < 7; ++f)
          acc[mo][f] = __builtin_amdgcn_mfma_f32_16x16x32_bf16(afc[mo], bfr[f], acc[mo][f], 0, 0, 0);
      #pragma unroll
      for (int mo = 0; mo < 4; ++mo) afc[mo] = afn[mo];
    }
    __syncthreads();   // drains staged gloads + all reads of current buf
  }

  float* ob = out + (size_t)b*NCO*NHW;
  #pragma unroll
  for (int mo = 0; mo < 4; ++mo) {
    #pragma unroll
    for (int rg = 0; rg < 4; ++rg) {
      const int co = wave_m*64 + mo*16 + kg*4 + rg;
      const float bv = bc[b*NCO + co];
      float* orow = ob + (size_t)co*NHW;
      #pragma unroll
      for (int f = 0; f < 7; ++f)
        orow[(r0 + rB[f])*56 + cB[f]] = acc[mo][f][rg] + bv;
    }
  }
}

extern "C" void kernel_launch(void* const* d_in, const int* in_sizes, int n_in,
                              void* d_out, int out_size, void* d_ws, size_t ws_size,
                              hipStream_t stream) {
  const float* x   = (const float*)d_in[0];
  const float* W   = (const float*)d_in[1];
  const float* bia = (const float*)d_in[2];
  const float* aw1 = (const float*)d_in[3];
  const float* aw2 = (const float*)d_in[4];
  float* out = (float*)d_out;
  char* ws = (char*)d_ws;
  float* attn   = (float*)(ws + WS_ATTN);
  float* bcm    = (float*)(ws + WS_BC);
  float* rowsum = (float*)(ws + WS_ROWSUM);
  __hip_bfloat16* wc = (__hip_bfloat16*)(ws + WS_WC);
  __hip_bfloat16* xt = (__hip_bfloat16*)(ws + WS_XT);

  xt_kernel<<<NB*58, 256, 0, stream>>>(x, xt, rowsum);
  attn_kernel<<<NB, 128, 0, stream>>>(rowsum, aw1, aw2, bia, attn, bcm);
  combine_kernel<<<256, 256, 0, stream>>>(W, attn, wc);
  conv_kernel<<<448, 256, 0, stream>>>((const unsigned short*)xt,
                                       (const unsigned short*)wc, bcm, out);
}